// Round 9
// baseline (253.976 us; speedup 1.0000x reference)
//
#include <hip/hip_runtime.h>

#define NNODES 50000
#define NEDGES 600000
#define HID 128
#define NLAYERS 3
#define NEG 0.01f
#define SCAN_B ((NNODES + 1023) / 1024)   // 49 blocks

typedef __attribute__((ext_vector_type(8))) short short8;
typedef __attribute__((ext_vector_type(4))) float f32x4;

__device__ __forceinline__ unsigned int f2bf(float f) {   // RNE f32 -> bf16 bits
    unsigned int u = __float_as_uint(f);
    return (u + 0x7fffu + ((u >> 16) & 1u)) >> 16;
}
__device__ __forceinline__ float bf2f(unsigned int h) {
    return __uint_as_float(h << 16);
}
__device__ __forceinline__ float bflo(unsigned int p) { return __uint_as_float(p << 16); }
__device__ __forceinline__ float bfhi(unsigned int p) { return __uint_as_float(p & 0xffff0000u); }

// ---------- CSR build (once per call; edge list is layer-invariant) ----------

__global__ __launch_bounds__(256) void zero_k(int* __restrict__ p, const int n) {
    const int i = blockIdx.x * 256 + threadIdx.x;
    if (i < n) p[i] = 0;
}

__global__ __launch_bounds__(256) void hist_k(const int* __restrict__ ei,
                                              int* __restrict__ deg) {
    const int e = blockIdx.x * blockDim.x + threadIdx.x;
    if (e < NEDGES) atomicAdd(&deg[ei[NEDGES + e]], 1);
}

__global__ __launch_bounds__(1024) void scan1_k(const int* __restrict__ deg,
                                                int* __restrict__ part,
                                                int* __restrict__ bsum) {
    __shared__ int s[1024];
    const int t = threadIdx.x;
    const int i = blockIdx.x * 1024 + t;
    const int v = (i < NNODES) ? deg[i] : 0;
    s[t] = v;
    __syncthreads();
    for (int d = 1; d < 1024; d <<= 1) {
        const int add = (t >= d) ? s[t - d] : 0;
        __syncthreads();
        s[t] += add;
        __syncthreads();
    }
    if (i < NNODES) part[i] = s[t] - v;
    if (t == 1023) bsum[blockIdx.x] = s[1023];
}

__global__ __launch_bounds__(1024) void scan2_k(const int* __restrict__ part,
                                                const int* __restrict__ bsum,
                                                int* __restrict__ off,
                                                int* __restrict__ cur) {
    const int b = blockIdx.x;
    const int t = threadIdx.x;
    const int lane = t & 63;
    int v = (lane < b) ? bsum[lane] : 0;
#pragma unroll
    for (int d = 1; d < 64; d <<= 1) v += __shfl_xor(v, d);
    const int i = b * 1024 + t;
    if (i < NNODES) {
        const int e = part[i] + v;
        off[i] = e;
        cur[i] = e;
    }
    if (b == 0 && t == 0) off[NNODES] = NEDGES;
}

// meta[slot] = {src, bf16(a0) | bf16(a1)<<16} packed in 64 bits, dst-grouped.
__global__ __launch_bounds__(256) void fill_k(const int* __restrict__ ei,
                                              const float* __restrict__ ea,
                                              int* __restrict__ cur,
                                              unsigned long long* __restrict__ meta) {
    const int e = blockIdx.x * blockDim.x + threadIdx.x;
    if (e < NEDGES) {
        const int s = ei[e];
        const int d = ei[NEDGES + e];
        const float a0 = ea[2 * e];
        const float a1 = ea[2 * e + 1];
        const int p = atomicAdd(&cur[d], 1);
        const unsigned long long m =
            (unsigned long long)(unsigned int)s |
            ((unsigned long long)(f2bf(a0) | (f2bf(a1) << 16)) << 32);
        __builtin_nontemporal_store(m, &meta[p]);
    }
}

// x (f32) -> hb (bf16 packed x2), layer-0 node features.
__global__ __launch_bounds__(256) void cvt_k(const float* __restrict__ x,
                                             unsigned int* __restrict__ hb) {
    const int i = blockIdx.x * 256 + threadIdx.x;
    if (i < NNODES * 64) {
        const float2 v = *(const float2*)(x + (size_t)i * 2);
        hb[i] = f2bf(v.x) | (f2bf(v.y) << 16);
    }
}

// ---------- W -> split-bf16 MFMA B-fragment layout (once, all layers) --------
__global__ __launch_bounds__(256) void wconv_k(const float* __restrict__ W,
                                               uint4* __restrict__ whf,
                                               uint4* __restrict__ wlf) {
    const int g = (blockIdx.x * 256 + threadIdx.x) >> 6;
    if (g >= NLAYERS * 32) return;
    const int lane = threadIdx.x & 63;
    const int l = g >> 5;
    const int kt = (g >> 3) & 3;
    const int nt = g & 7;
    const int n = nt * 16 + (lane & 15);
    const int k0 = kt * 32 + (lane >> 4) * 8;
    unsigned int hh[8], ll[8];
#pragma unroll
    for (int j = 0; j < 8; ++j) {
        const float w = W[l * HID * HID + (k0 + j) * HID + n];
        const unsigned int wh = f2bf(w);
        hh[j] = wh;
        ll[j] = f2bf(w - bf2f(wh));
    }
    uint4 ph, pl;
    ph.x = hh[0] | (hh[1] << 16); ph.y = hh[2] | (hh[3] << 16);
    ph.z = hh[4] | (hh[5] << 16); ph.w = hh[6] | (hh[7] << 16);
    pl.x = ll[0] | (ll[1] << 16); pl.y = ll[2] | (ll[3] << 16);
    pl.z = ll[4] | (ll[5] << 16); pl.w = ll[6] | (ll[7] << 16);
    const int idx = ((l * 4 + kt) * 8 + nt) * 64 + lane;
    whf[idx] = ph;
    wlf[idx] = pl;
}

// ---------- Aggregation: one wave per node, bf16 gathers, 8-deep MLP ---------
// vh[n] = bf16( h[n] + sum_{incoming e} relu(h[src_e] + ea_e @ Wl + bl) )
__global__ __launch_bounds__(256) void agg_k(
    const unsigned int* __restrict__ hb,  // [N*64] bf16x2 node features
    const unsigned long long* __restrict__ meta,
    const float* __restrict__ Wl,   // [2, HID]
    const float* __restrict__ bl,   // [HID]
    const int* __restrict__ off,
    unsigned int* __restrict__ vh)  // [N*64] packed bf16x2
{
    const int node = blockIdx.x * 4 + (threadIdx.x >> 6);
    if (node >= NNODES) return;
    const int lane = threadIdx.x & 63;
    const int f0 = lane << 1;
    const float2 w0 = *(const float2*)(Wl + f0);
    const float2 w1 = *(const float2*)(Wl + HID + f0);
    const float2 bb = *(const float2*)(bl + f0);
    const unsigned int hp = hb[(size_t)node * 64 + lane];
    float2 acc = make_float2(bflo(hp), bfhi(hp));   // (1+eps)*h, eps=0
    int idx = off[node];
    const int e1 = off[node + 1];
    for (; idx + 8 <= e1; idx += 8) {
        unsigned long long m[8];
#pragma unroll
        for (int j = 0; j < 8; ++j) m[j] = meta[idx + j];
        unsigned int g[8];
#pragma unroll
        for (int j = 0; j < 8; ++j)
            g[j] = hb[(size_t)(unsigned int)m[j] * 64 + lane];
#pragma unroll
        for (int j = 0; j < 8; ++j) {
            const unsigned int ap = (unsigned int)(m[j] >> 32);
            const float a0 = bflo(ap), a1 = bfhi(ap);
            acc.x += fmaxf(bflo(g[j]) + fmaf(a0, w0.x, fmaf(a1, w1.x, bb.x)), 0.f);
            acc.y += fmaxf(bfhi(g[j]) + fmaf(a0, w0.y, fmaf(a1, w1.y, bb.y)), 0.f);
        }
    }
    if (idx + 4 <= e1) {
        unsigned long long m[4];
#pragma unroll
        for (int j = 0; j < 4; ++j) m[j] = meta[idx + j];
        unsigned int g[4];
#pragma unroll
        for (int j = 0; j < 4; ++j)
            g[j] = hb[(size_t)(unsigned int)m[j] * 64 + lane];
#pragma unroll
        for (int j = 0; j < 4; ++j) {
            const unsigned int ap = (unsigned int)(m[j] >> 32);
            const float a0 = bflo(ap), a1 = bfhi(ap);
            acc.x += fmaxf(bflo(g[j]) + fmaf(a0, w0.x, fmaf(a1, w1.x, bb.x)), 0.f);
            acc.y += fmaxf(bfhi(g[j]) + fmaf(a0, w0.y, fmaf(a1, w1.y, bb.y)), 0.f);
        }
        idx += 4;
    }
    for (; idx < e1; ++idx) {
        const unsigned long long m = meta[idx];
        const unsigned int g = hb[(size_t)(unsigned int)m * 64 + lane];
        const unsigned int ap = (unsigned int)(m >> 32);
        const float a0 = bflo(ap), a1 = bfhi(ap);
        acc.x += fmaxf(bflo(g) + fmaf(a0, w0.x, fmaf(a1, w1.x, bb.x)), 0.f);
        acc.y += fmaxf(bfhi(g) + fmaf(a0, w0.y, fmaf(a1, w1.y, bb.y)), 0.f);
    }
    vh[(size_t)node * 64 + lane] = f2bf(acc.x) | (f2bf(acc.y) << 16);
}

// ---------- MFMA GEMM: leakyrelu(bf16(v) @ (wh+wl) + bias) -------------------
// Writes bf16 hb (layers 0,1) or f32 out (final layer).
__global__ __launch_bounds__(256) void gemm_k(
    const unsigned int* __restrict__ vh,   // [N][128] bf16 (packed x2)
    const uint4* __restrict__ whf,         // this layer's [4][8][64] frags
    const uint4* __restrict__ wlf,
    const float* __restrict__ bias,        // [HID]
    float* __restrict__ out,               // [N, HID] f32 (final layer)
    unsigned short* __restrict__ hbo,      // [N, HID] bf16 (layers 0,1)
    const int last)
{
    const int tid = threadIdx.x;
    const int wave = tid >> 6;
    const int lane = tid & 63;
    const int rowbase = blockIdx.x * 64 + wave * 16;
    const int arow = rowbase + (lane & 15);
    const int arowc = arow < NNODES ? arow : NNODES - 1;
    const uint4* vh4 = (const uint4*)vh;

    short8 a[4];
#pragma unroll
    for (int kt = 0; kt < 4; ++kt) {
        uint4 t = vh4[(size_t)arowc * 16 + kt * 4 + (lane >> 4)];
        a[kt] = *(short8*)&t;
    }

    const int crow0 = rowbase + (lane >> 4) * 4;
    const int ncol = lane & 15;
#pragma unroll
    for (int nt = 0; nt < 8; ++nt) {
        const float bv = bias[nt * 16 + ncol];
        f32x4 acc = {bv, bv, bv, bv};
#pragma unroll
        for (int kt = 0; kt < 4; ++kt) {
            uint4 th = whf[(kt * 8 + nt) * 64 + lane];
            uint4 tl = wlf[(kt * 8 + nt) * 64 + lane];
            acc = __builtin_amdgcn_mfma_f32_16x16x32_bf16(a[kt], *(short8*)&th, acc, 0, 0, 0);
            acc = __builtin_amdgcn_mfma_f32_16x16x32_bf16(a[kt], *(short8*)&tl, acc, 0, 0, 0);
        }
#pragma unroll
        for (int r = 0; r < 4; ++r) {
            const int rr = crow0 + r;
            if (rr < NNODES) {
                float v = acc[r];
                v = v >= 0.f ? v : NEG * v;
                if (last) out[(size_t)rr * HID + nt * 16 + ncol] = v;
                else      hbo[(size_t)rr * HID + nt * 16 + ncol] = (unsigned short)f2bf(v);
            }
        }
    }
}

extern "C" void kernel_launch(void* const* d_in, const int* in_sizes, int n_in,
                              void* d_out, int out_size, void* d_ws, size_t ws_size,
                              hipStream_t stream) {
    const float* x  = (const float*)d_in[0];
    const int*   ei = (const int*)d_in[1];
    const float* ea = (const float*)d_in[2];
    const float* Wl = (const float*)d_in[3];
    const float* bl = (const float*)d_in[4];
    const float* W  = (const float*)d_in[5];
    const float* b  = (const float*)d_in[6];

    float* h = (float*)d_out;                              // final f32 output

    unsigned long long* meta = (unsigned long long*)d_ws;  // [E] {src, a0|a1 bf16}
    unsigned int* vh = (unsigned int*)(meta + NEDGES);     // [N*64] bf16x2 GEMM input
    unsigned int* hb = vh + (size_t)NNODES * 64;           // [N*64] bf16x2 node feats
    uint4* whf = (uint4*)(hb + (size_t)NNODES * 64);       // [3][4][8][64]
    uint4* wlf = whf + NLAYERS * 4 * 8 * 64;
    int* off  = (int*)(wlf + NLAYERS * 4 * 8 * 64);        // [N+1] (doubles as histogram)
    int* cur  = off + NNODES + 1;
    int* part = cur + NNODES;
    int* bsum = part + NNODES;

    // CSR metadata + W fragments + bf16(x) — reused/one-shot.
    zero_k<<<(NNODES + 256) / 256, 256, 0, stream>>>(off, NNODES + 1);
    hist_k<<<(NEDGES + 255) / 256, 256, 0, stream>>>(ei, off);
    scan1_k<<<SCAN_B, 1024, 0, stream>>>(off, part, bsum);
    scan2_k<<<SCAN_B, 1024, 0, stream>>>(part, bsum, off, cur);
    fill_k<<<(NEDGES + 255) / 256, 256, 0, stream>>>(ei, ea, cur, meta);
    wconv_k<<<24, 256, 0, stream>>>(W, whf, wlf);
    cvt_k<<<(NNODES * 64 + 255) / 256, 256, 0, stream>>>(x, hb);

    for (int l = 0; l < NLAYERS; ++l) {
        agg_k<<<(NNODES + 3) / 4, 256, 0, stream>>>(
            hb, meta, Wl + (size_t)l * 2 * HID, bl + (size_t)l * HID, off, vh);
        gemm_k<<<(NNODES + 63) / 64, 256, 0, stream>>>(
            vh, whf + (size_t)l * 4 * 8 * 64, wlf + (size_t)l * 4 * 8 * 64,
            b + (size_t)l * HID, h, (unsigned short*)hb, l == NLAYERS - 1);
    }
}

// Round 10
// 235.448 us; speedup vs baseline: 1.0787x; 1.0787x over previous
//
#include <hip/hip_runtime.h>

#define NNODES 50000
#define NEDGES 600000
#define HID 128
#define NLAYERS 3
#define NEG 0.01f
#define SCAN_B ((NNODES + 1023) / 1024)   // 49 blocks
#define FILL_BPG 150                      // fill blocks per XCD group

typedef __attribute__((ext_vector_type(8))) short short8;
typedef __attribute__((ext_vector_type(4))) float f32x4;

__device__ __forceinline__ unsigned int f2bf(float f) {   // RNE f32 -> bf16 bits
    unsigned int u = __float_as_uint(f);
    return (u + 0x7fffu + ((u >> 16) & 1u)) >> 16;
}
__device__ __forceinline__ float bf2f(unsigned int h) {
    return __uint_as_float(h << 16);
}
__device__ __forceinline__ float bflo(unsigned int p) { return __uint_as_float(p << 16); }
__device__ __forceinline__ float bfhi(unsigned int p) { return __uint_as_float(p & 0xffff0000u); }

// ---------- CSR build (once per call; edge list is layer-invariant) ----------

__global__ __launch_bounds__(256) void zero_k(int* __restrict__ p, const int n) {
    const int i = blockIdx.x * 256 + threadIdx.x;
    if (i < n) p[i] = 0;
}

__global__ __launch_bounds__(256) void hist_k(const int* __restrict__ ei,
                                              int* __restrict__ deg) {
    const int e = blockIdx.x * blockDim.x + threadIdx.x;
    if (e < NEDGES) atomicAdd(&deg[ei[NEDGES + e]], 1);
}

__global__ __launch_bounds__(1024) void scan1_k(const int* __restrict__ deg,
                                                int* __restrict__ part,
                                                int* __restrict__ bsum) {
    __shared__ int s[1024];
    const int t = threadIdx.x;
    const int i = blockIdx.x * 1024 + t;
    const int v = (i < NNODES) ? deg[i] : 0;
    s[t] = v;
    __syncthreads();
    for (int d = 1; d < 1024; d <<= 1) {
        const int add = (t >= d) ? s[t - d] : 0;
        __syncthreads();
        s[t] += add;
        __syncthreads();
    }
    if (i < NNODES) part[i] = s[t] - v;
    if (t == 1023) bsum[blockIdx.x] = s[1023];
}

__global__ __launch_bounds__(1024) void scan2_k(const int* __restrict__ part,
                                                const int* __restrict__ bsum,
                                                int* __restrict__ off,
                                                int* __restrict__ cur) {
    const int b = blockIdx.x;
    const int t = threadIdx.x;
    const int lane = t & 63;
    int v = (lane < b) ? bsum[lane] : 0;
#pragma unroll
    for (int d = 1; d < 64; d <<= 1) v += __shfl_xor(v, d);
    const int i = b * 1024 + t;
    if (i < NNODES) {
        const int e = part[i] + v;
        off[i] = e;
        cur[i] = e;
    }
    if (b == 0 && t == 0) off[NNODES] = NEDGES;
}

// XCD-partitioned scatter: group g = blockIdx.x%8 (lands on XCD g under the
// round-robin dispatch) owns dst range [g*6250,(g+1)*6250). All writers of a
// meta cache line are then on one XCD -> line merges in its L2 before
// writeback (kills the 8x partial-line write amplification).
__global__ __launch_bounds__(256) void fill_k(const int* __restrict__ ei,
                                              const float* __restrict__ ea,
                                              int* __restrict__ cur,
                                              unsigned long long* __restrict__ meta) {
    const int g = blockIdx.x & 7;
    const int bg = blockIdx.x >> 3;
    const int dlo = g * (NNODES / 8);
    const int dhi = dlo + (NNODES / 8);
    const int stride = FILL_BPG * 256;
    for (int e = bg * 256 + threadIdx.x; e < NEDGES; e += stride) {
        const int d = ei[NEDGES + e];
        if (d >= dlo && d < dhi) {
            const int s = ei[e];
            const float2 av = *(const float2*)(ea + 2 * e);
            const int p = atomicAdd(&cur[d], 1);
            meta[p] = (unsigned long long)(unsigned int)s |
                      ((unsigned long long)(f2bf(av.x) | (f2bf(av.y) << 16)) << 32);
        }
    }
}

// x (f32) -> hb (bf16 packed x2), layer-0 node features.
__global__ __launch_bounds__(256) void cvt_k(const float* __restrict__ x,
                                             unsigned int* __restrict__ hb) {
    const int i = blockIdx.x * 256 + threadIdx.x;
    if (i < NNODES * 64) {
        const float2 v = *(const float2*)(x + (size_t)i * 2);
        hb[i] = f2bf(v.x) | (f2bf(v.y) << 16);
    }
}

// ---------- W -> split-bf16 MFMA B-fragment layout (once, all layers) --------
__global__ __launch_bounds__(256) void wconv_k(const float* __restrict__ W,
                                               uint4* __restrict__ whf,
                                               uint4* __restrict__ wlf) {
    const int g = (blockIdx.x * 256 + threadIdx.x) >> 6;
    if (g >= NLAYERS * 32) return;
    const int lane = threadIdx.x & 63;
    const int l = g >> 5;
    const int kt = (g >> 3) & 3;
    const int nt = g & 7;
    const int n = nt * 16 + (lane & 15);
    const int k0 = kt * 32 + (lane >> 4) * 8;
    unsigned int hh[8], ll[8];
#pragma unroll
    for (int j = 0; j < 8; ++j) {
        const float w = W[l * HID * HID + (k0 + j) * HID + n];
        const unsigned int wh = f2bf(w);
        hh[j] = wh;
        ll[j] = f2bf(w - bf2f(wh));
    }
    uint4 ph, pl;
    ph.x = hh[0] | (hh[1] << 16); ph.y = hh[2] | (hh[3] << 16);
    ph.z = hh[4] | (hh[5] << 16); ph.w = hh[6] | (hh[7] << 16);
    pl.x = ll[0] | (ll[1] << 16); pl.y = ll[2] | (ll[3] << 16);
    pl.z = ll[4] | (ll[5] << 16); pl.w = ll[6] | (ll[7] << 16);
    const int idx = ((l * 4 + kt) * 8 + nt) * 64 + lane;
    whf[idx] = ph;
    wlf[idx] = pl;
}

// ---------- Aggregation: one wave per node, bf16 gathers, 8-deep MLP ---------
// vh[n] = bf16( h[n] + sum_{incoming e} relu(h[src_e] + ea_e @ Wl + bl) )
__global__ __launch_bounds__(256) void agg_k(
    const unsigned int* __restrict__ hb,  // [N*64] bf16x2 node features
    const unsigned long long* __restrict__ meta,
    const float* __restrict__ Wl,   // [2, HID]
    const float* __restrict__ bl,   // [HID]
    const int* __restrict__ off,
    unsigned int* __restrict__ vh)  // [N*64] packed bf16x2
{
    const int node = blockIdx.x * 4 + (threadIdx.x >> 6);
    if (node >= NNODES) return;
    const int lane = threadIdx.x & 63;
    const int f0 = lane << 1;
    const float2 w0 = *(const float2*)(Wl + f0);
    const float2 w1 = *(const float2*)(Wl + HID + f0);
    const float2 bb = *(const float2*)(bl + f0);
    const unsigned int hp = hb[(size_t)node * 64 + lane];
    float2 acc = make_float2(bflo(hp), bfhi(hp));   // (1+eps)*h, eps=0
    int idx = off[node];
    const int e1 = off[node + 1];
    for (; idx + 8 <= e1; idx += 8) {
        unsigned long long m[8];
#pragma unroll
        for (int j = 0; j < 8; ++j) m[j] = meta[idx + j];
        unsigned int g[8];
#pragma unroll
        for (int j = 0; j < 8; ++j)
            g[j] = hb[(size_t)(unsigned int)m[j] * 64 + lane];
#pragma unroll
        for (int j = 0; j < 8; ++j) {
            const unsigned int ap = (unsigned int)(m[j] >> 32);
            const float a0 = bflo(ap), a1 = bfhi(ap);
            acc.x += fmaxf(bflo(g[j]) + fmaf(a0, w0.x, fmaf(a1, w1.x, bb.x)), 0.f);
            acc.y += fmaxf(bfhi(g[j]) + fmaf(a0, w0.y, fmaf(a1, w1.y, bb.y)), 0.f);
        }
    }
    if (idx + 4 <= e1) {
        unsigned long long m[4];
#pragma unroll
        for (int j = 0; j < 4; ++j) m[j] = meta[idx + j];
        unsigned int g[4];
#pragma unroll
        for (int j = 0; j < 4; ++j)
            g[j] = hb[(size_t)(unsigned int)m[j] * 64 + lane];
#pragma unroll
        for (int j = 0; j < 4; ++j) {
            const unsigned int ap = (unsigned int)(m[j] >> 32);
            const float a0 = bflo(ap), a1 = bfhi(ap);
            acc.x += fmaxf(bflo(g[j]) + fmaf(a0, w0.x, fmaf(a1, w1.x, bb.x)), 0.f);
            acc.y += fmaxf(bfhi(g[j]) + fmaf(a0, w0.y, fmaf(a1, w1.y, bb.y)), 0.f);
        }
        idx += 4;
    }
    for (; idx < e1; ++idx) {
        const unsigned long long m = meta[idx];
        const unsigned int g = hb[(size_t)(unsigned int)m * 64 + lane];
        const unsigned int ap = (unsigned int)(m >> 32);
        const float a0 = bflo(ap), a1 = bfhi(ap);
        acc.x += fmaxf(bflo(g) + fmaf(a0, w0.x, fmaf(a1, w1.x, bb.x)), 0.f);
        acc.y += fmaxf(bfhi(g) + fmaf(a0, w0.y, fmaf(a1, w1.y, bb.y)), 0.f);
    }
    vh[(size_t)node * 64 + lane] = f2bf(acc.x) | (f2bf(acc.y) << 16);
}

// ---------- MFMA GEMM: leakyrelu(bf16(v) @ (wh+wl) + bias) -------------------
// Writes bf16 hb (layers 0,1) or f32 out (final layer).
__global__ __launch_bounds__(256) void gemm_k(
    const unsigned int* __restrict__ vh,   // [N][128] bf16 (packed x2)
    const uint4* __restrict__ whf,         // this layer's [4][8][64] frags
    const uint4* __restrict__ wlf,
    const float* __restrict__ bias,        // [HID]
    float* __restrict__ out,               // [N, HID] f32 (final layer)
    unsigned short* __restrict__ hbo,      // [N, HID] bf16 (layers 0,1)
    const int last)
{
    const int tid = threadIdx.x;
    const int wave = tid >> 6;
    const int lane = tid & 63;
    const int rowbase = blockIdx.x * 64 + wave * 16;
    const int arow = rowbase + (lane & 15);
    const int arowc = arow < NNODES ? arow : NNODES - 1;
    const uint4* vh4 = (const uint4*)vh;

    short8 a[4];
#pragma unroll
    for (int kt = 0; kt < 4; ++kt) {
        uint4 t = vh4[(size_t)arowc * 16 + kt * 4 + (lane >> 4)];
        a[kt] = *(short8*)&t;
    }

    const int crow0 = rowbase + (lane >> 4) * 4;
    const int ncol = lane & 15;
#pragma unroll
    for (int nt = 0; nt < 8; ++nt) {
        const float bv = bias[nt * 16 + ncol];
        f32x4 acc = {bv, bv, bv, bv};
#pragma unroll
        for (int kt = 0; kt < 4; ++kt) {
            uint4 th = whf[(kt * 8 + nt) * 64 + lane];
            uint4 tl = wlf[(kt * 8 + nt) * 64 + lane];
            acc = __builtin_amdgcn_mfma_f32_16x16x32_bf16(a[kt], *(short8*)&th, acc, 0, 0, 0);
            acc = __builtin_amdgcn_mfma_f32_16x16x32_bf16(a[kt], *(short8*)&tl, acc, 0, 0, 0);
        }
#pragma unroll
        for (int r = 0; r < 4; ++r) {
            const int rr = crow0 + r;
            if (rr < NNODES) {
                float v = acc[r];
                v = v >= 0.f ? v : NEG * v;
                if (last) out[(size_t)rr * HID + nt * 16 + ncol] = v;
                else      hbo[(size_t)rr * HID + nt * 16 + ncol] = (unsigned short)f2bf(v);
            }
        }
    }
}

extern "C" void kernel_launch(void* const* d_in, const int* in_sizes, int n_in,
                              void* d_out, int out_size, void* d_ws, size_t ws_size,
                              hipStream_t stream) {
    const float* x  = (const float*)d_in[0];
    const int*   ei = (const int*)d_in[1];
    const float* ea = (const float*)d_in[2];
    const float* Wl = (const float*)d_in[3];
    const float* bl = (const float*)d_in[4];
    const float* W  = (const float*)d_in[5];
    const float* b  = (const float*)d_in[6];

    float* h = (float*)d_out;                              // final f32 output

    unsigned long long* meta = (unsigned long long*)d_ws;  // [E] {src, a0|a1 bf16}
    unsigned int* vh = (unsigned int*)(meta + NEDGES);     // [N*64] bf16x2 GEMM input
    unsigned int* hb = vh + (size_t)NNODES * 64;           // [N*64] bf16x2 node feats
    uint4* whf = (uint4*)(hb + (size_t)NNODES * 64);       // [3][4][8][64]
    uint4* wlf = whf + NLAYERS * 4 * 8 * 64;
    int* off  = (int*)(wlf + NLAYERS * 4 * 8 * 64);        // [N+1] (doubles as histogram)
    int* cur  = off + NNODES + 1;
    int* part = cur + NNODES;
    int* bsum = part + NNODES;

    // CSR metadata + W fragments + bf16(x) — reused/one-shot.
    zero_k<<<(NNODES + 256) / 256, 256, 0, stream>>>(off, NNODES + 1);
    hist_k<<<(NEDGES + 255) / 256, 256, 0, stream>>>(ei, off);
    scan1_k<<<SCAN_B, 1024, 0, stream>>>(off, part, bsum);
    scan2_k<<<SCAN_B, 1024, 0, stream>>>(part, bsum, off, cur);
    fill_k<<<8 * FILL_BPG, 256, 0, stream>>>(ei, ea, cur, meta);
    wconv_k<<<24, 256, 0, stream>>>(W, whf, wlf);
    cvt_k<<<(NNODES * 64 + 255) / 256, 256, 0, stream>>>(x, hb);

    for (int l = 0; l < NLAYERS; ++l) {
        agg_k<<<(NNODES + 3) / 4, 256, 0, stream>>>(
            hb, meta, Wl + (size_t)l * 2 * HID, bl + (size_t)l * HID, off, vh);
        gemm_k<<<(NNODES + 63) / 64, 256, 0, stream>>>(
            vh, whf + (size_t)l * 4 * 8 * 64, wlf + (size_t)l * 4 * 8 * 64,
            b + (size_t)l * HID, h, (unsigned short*)hb, l == NLAYERS - 1);
    }
}